// Round 7
// baseline (161.438 us; speedup 1.0000x reference)
//
#include <hip/hip_runtime.h>

#define NN 8192
#define MM 8192
#define DD 256
#define NPART 8
#define MPART (MM / NPART)   // 1024
#define BK 32
#define NT (MPART / BK)      // 32
#define QT 32

typedef short bf16x8 __attribute__((ext_vector_type(8)));
typedef short bf16x4 __attribute__((ext_vector_type(4)));
typedef float f32x4 __attribute__((ext_vector_type(4)));
typedef float f32x16 __attribute__((ext_vector_type(16)));
typedef unsigned int u32;
typedef u32 u32x4 __attribute__((ext_vector_type(4)));

#define GLL16(src, dst) __builtin_amdgcn_global_load_lds( \
    (__attribute__((address_space(1))) void*)(src), \
    (__attribute__((address_space(3))) void*)(dst), 16, 0, 0)

static __device__ __forceinline__ short f2bf(float f) {
    unsigned u = __float_as_uint(f);
    u += 0x7fffu + ((u >> 16) & 1u);   // RNE
    return (short)(u >> 16);
}

static __device__ __forceinline__ u32 cvtpk(float lo, float hi) {
    u32 r;
    asm("v_cvt_pk_bf16_f32 %0, %1, %2" : "=v"(r) : "v"(lo), "v"(hi));
    return r;
}

// ---------------- projection: y = x @ W^T + b  -> bf16 ----------------
// grid 1536 = 3 mats x 128 row-tiles x 4 col-tiles; 256 threads
__global__ __launch_bounds__(256, 2) void proj_kernel(
    const float* __restrict__ xq, const float* __restrict__ xkv,
    const float* __restrict__ Wq, const float* __restrict__ bq,
    const float* __restrict__ Wk, const float* __restrict__ bk,
    const float* __restrict__ Wv, const float* __restrict__ bv,
    short* __restrict__ qo, short* __restrict__ ko, short* __restrict__ vp)
{
    __shared__ short Xs[64][264];
    __shared__ short Ws[64][264];

    const int bid = blockIdx.x;
    const int mat = bid >> 9;
    const int t = bid & 511;
    const int rt = t >> 2;
    const int ct = t & 3;
    const float* __restrict__ X = (mat == 0) ? xq : xkv;
    const float* __restrict__ W = (mat == 0) ? Wq : ((mat == 1) ? Wk : Wv);
    const float* __restrict__ bias = (mat == 0) ? bq : ((mat == 1) ? bk : bv);

    const int tid = threadIdx.x;
    const int lane = tid & 63;
    const int wv = tid >> 6;
    const int l15 = lane & 15;
    const int lg = lane >> 4;

    #pragma unroll
    for (int i = 0; i < 16; ++i) {
        int c = i * 256 + tid;
        int row = c >> 6;
        int col4 = (c & 63) << 2;
        f32x4 xv = *reinterpret_cast<const f32x4*>(X + (size_t)(rt * 64 + row) * DD + col4);
        f32x4 wr = *reinterpret_cast<const f32x4*>(W + (size_t)(ct * 64 + row) * DD + col4);
        bf16x4 xb, wb;
        #pragma unroll
        for (int j = 0; j < 4; ++j) { xb[j] = f2bf(xv[j]); wb[j] = f2bf(wr[j]); }
        *reinterpret_cast<bf16x4*>(&Xs[row][col4]) = xb;
        *reinterpret_cast<bf16x4*>(&Ws[row][col4]) = wb;
    }
    __syncthreads();

    f32x4 acc[4];
    #pragma unroll
    for (int f = 0; f < 4; ++f) acc[f] = f32x4{0.f, 0.f, 0.f, 0.f};

    #pragma unroll
    for (int kk = 0; kk < 8; ++kk) {
        bf16x8 a = *reinterpret_cast<const bf16x8*>(&Xs[wv * 16 + l15][kk * 32 + lg * 8]);
        #pragma unroll
        for (int f = 0; f < 4; ++f) {
            bf16x8 b = *reinterpret_cast<const bf16x8*>(&Ws[f * 16 + l15][kk * 32 + lg * 8]);
            acc[f] = __builtin_amdgcn_mfma_f32_16x16x32_bf16(a, b, acc[f], 0, 0, 0);
        }
    }

    #pragma unroll
    for (int f = 0; f < 4; ++f) {
        const int o = ct * 64 + f * 16 + l15;
        const float bsv = bias[o];
        if (mat == 2) {
            // V panels: vp[(m>>5)*8192 + d*32 + (m&31)]
            bf16x4 pk;
            #pragma unroll
            for (int r = 0; r < 4; ++r) pk[r] = f2bf(acc[f][r] + bsv);
            const int mb = rt * 64 + wv * 16 + lg * 4;
            *reinterpret_cast<bf16x4*>(&vp[(size_t)(mb >> 5) * 8192 + o * 32 + (mb & 31)]) = pk;
        } else {
            // q: fold 1/sqrt(D)=1/16 and log2(e) (softmax in exp2 domain)
            const float sc = (mat == 0) ? 0.0625f * 1.44269504089f : 1.0f;
            short* __restrict__ dst = (mat == 0) ? qo : ko;
            #pragma unroll
            for (int r = 0; r < 4; ++r) {
                const int rowg = rt * 64 + wv * 16 + lg * 4 + r;
                dst[(size_t)rowg * DD + o] = f2bf((acc[f][r] + bsv) * sc);
            }
        }
    }
}

// ---------------- flash attention: BK=32, 4 waves, 2 blocks/CU ----------------
// grid: 512 = 64 q-tiles(128 q) x 8 parts; 256 threads (4 waves x 32 q/wave)
// Defer-max online softmax (proven numerics); two blocks per CU so one block's
// compute covers the other's barrier drain.
__global__ __launch_bounds__(256, 2) void attn_kernel(
    const short* __restrict__ qg, const short* __restrict__ kg,
    const short* __restrict__ vp, float* __restrict__ outpT,
    float* __restrict__ statm, float* __restrict__ statl)
{
    extern __shared__ short lds[];
    short* KsBase = lds;            // [2][8192] : [m 32][512B], phys chunk = log ^ (m&15)
    short* VsBase = lds + 16384;    // [2][8192] : [d 256][64B],  phys chunk = (log + (d&3)) & 3

    const int bid = blockIdx.x;
    const int p = bid & 7;
    const int qt = bid >> 3;
    const int q0 = qt * 128;
    const int tile0 = p * NT;

    const int tid = threadIdx.x;
    const int lane = tid & 63;
    const int w = tid >> 6;
    const int l31 = lane & 31;
    const int h = lane >> 5;

    // Q B-frags: qf[kt] = Q[q0+w*32+l31][kt*16 + h*8 .. +7]
    bf16x8 qf[16];
    {
        const short* qr = qg + (size_t)(q0 + w * 32 + l31) * DD + h * 8;
        #pragma unroll
        for (int kt = 0; kt < 16; ++kt)
            qf[kt] = *reinterpret_cast<const bf16x8*>(qr + kt * 16);
    }

    // staging source offsets (shorts), pre-permuted for swizzled LDS reads
    int koff[4], voff[4], jdst[4];
    #pragma unroll
    for (int i = 0; i < 4; ++i) {
        const int j = w * 4 + i;                  // 0..15
        const int m = 2 * j + h;                  // K row 0..31
        koff[i] = m * 256 + ((l31 ^ (m & 15)) << 3);
        const int d = j * 16 + (lane >> 2);       // V row 0..255
        const int cl = ((lane & 3) - (d & 3)) & 3;
        voff[i] = d * 32 + (cl << 3);
        jdst[i] = __builtin_amdgcn_readfirstlane(j * 512);
    }

    f32x16 o[8];
    #pragma unroll
    for (int dt = 0; dt < 8; ++dt)
        #pragma unroll
        for (int i = 0; i < 16; ++i) o[dt][i] = 0.f;
    float mrun = -1e30f, lrun = 0.f;

    // prologue: stage tile 0
    #pragma unroll
    for (int i = 0; i < 4; ++i) {
        GLL16(kg + (size_t)tile0 * 8192 + koff[i], KsBase + jdst[i]);
        GLL16(vp + (size_t)tile0 * 8192 + voff[i], VsBase + jdst[i]);
    }
    __syncthreads();

    int cur = 0;
    #pragma unroll 1
    for (int t = 0; t < NT; ++t) {
        if (t + 1 < NT) {
            const size_t tb = (size_t)(tile0 + t + 1) * 8192;
            short* kd = KsBase + (cur ^ 1) * 8192;
            short* vd = VsBase + (cur ^ 1) * 8192;
            #pragma unroll
            for (int i = 0; i < 4; ++i) {
                GLL16(kg + tb + koff[i], kd + jdst[i]);
                GLL16(vp + tb + voff[i], vd + jdst[i]);
            }
        }

        // S^T[m 32][q 32] = K · Q^T : two independent 8-deep chains
        f32x16 s0, s1;
        #pragma unroll
        for (int i = 0; i < 16; ++i) { s0[i] = 0.f; s1[i] = 0.f; }
        const char* kb = (const char*)(KsBase + cur * 8192);
        #pragma unroll
        for (int kt = 0; kt < 8; ++kt) {
            const int cA = ((kt * 2 + h) ^ (l31 & 15)) << 4;
            const int cB = (((kt + 8) * 2 + h) ^ (l31 & 15)) << 4;
            bf16x8 a0 = *reinterpret_cast<const bf16x8*>(kb + l31 * 512 + cA);
            bf16x8 a1 = *reinterpret_cast<const bf16x8*>(kb + l31 * 512 + cB);
            s0 = __builtin_amdgcn_mfma_f32_32x32x16_bf16(a0, qf[kt], s0, 0, 0, 0);
            s1 = __builtin_amdgcn_mfma_f32_32x32x16_bf16(a1, qf[kt + 8], s1, 0, 0, 0);
        }
        f32x16 s;
        #pragma unroll
        for (int i = 0; i < 16; ++i) s[i] = s0[i] + s1[i];

        // defer-max online softmax; q = l31 lane-local
        float mx;
        {
            float a0 = fmaxf(fmaxf(s[0], s[1]), fmaxf(s[2], s[3]));
            float a1 = fmaxf(fmaxf(s[4], s[5]), fmaxf(s[6], s[7]));
            float a2 = fmaxf(fmaxf(s[8], s[9]), fmaxf(s[10], s[11]));
            float a3 = fmaxf(fmaxf(s[12], s[13]), fmaxf(s[14], s[15]));
            mx = fmaxf(fmaxf(a0, a1), fmaxf(a2, a3));
            mx = fmaxf(mx, __shfl_xor(mx, 32));
        }
        if (__any(mx > mrun + 11.5f)) {       // defer-max (log2 domain)
            const float mn = fmaxf(mrun, mx);
            const float al = __builtin_amdgcn_exp2f(mrun - mn);
            mrun = mn;
            lrun *= al;
            #pragma unroll
            for (int dt = 0; dt < 8; ++dt)
                #pragma unroll
                for (int i = 0; i < 16; ++i) o[dt][i] *= al;
        }
        #pragma unroll
        for (int i = 0; i < 16; ++i) s[i] = __builtin_amdgcn_exp2f(s[i] - mrun);
        {
            float r0 = ((s[0] + s[1]) + (s[2] + s[3])) + ((s[4] + s[5]) + (s[6] + s[7]));
            float r1 = ((s[8] + s[9]) + (s[10] + s[11])) + ((s[12] + s[13]) + (s[14] + s[15]));
            float rs = r0 + r1;
            rs += __shfl_xor(rs, 32);
            lrun += rs;
        }

        // P -> 2 B-frags (m 0..15, 16..31)
        bf16x8 pb[2];
        #pragma unroll
        for (int g = 0; g < 2; ++g) {
            u32 pa = cvtpk(s[g * 8 + 0], s[g * 8 + 1]);
            u32 pbq = cvtpk(s[g * 8 + 2], s[g * 8 + 3]);
            u32 pc = cvtpk(s[g * 8 + 4], s[g * 8 + 5]);
            u32 pd = cvtpk(s[g * 8 + 6], s[g * 8 + 7]);
            const u32 xa = (u32)__shfl_xor((int)pa, 32);
            const u32 xb = (u32)__shfl_xor((int)pbq, 32);
            const u32 xc = (u32)__shfl_xor((int)pc, 32);
            const u32 xd = (u32)__shfl_xor((int)pd, 32);
            u32x4 bb;
            bb[0] = h ? xc : pa;
            bb[1] = h ? xd : pbq;
            bb[2] = h ? pc : xa;
            bb[3] = h ? pd : xb;
            pb[g] = __builtin_bit_cast(bf16x8, bb);
        }

        // O^T[d 256][q 32] += V^T · P (8 independent 2-chains)
        const char* vb = (const char*)(VsBase + cur * 8192);
        #pragma unroll
        for (int dt = 0; dt < 8; ++dt) {
            const int d = dt * 32 + l31;
            const char* rbase = vb + d * 64;
            const int rot = d & 3;
            bf16x8 a0 = *reinterpret_cast<const bf16x8*>(rbase + (((0 + h + rot) & 3) << 4));
            bf16x8 a1 = *reinterpret_cast<const bf16x8*>(rbase + (((2 + h + rot) & 3) << 4));
            o[dt] = __builtin_amdgcn_mfma_f32_32x32x16_bf16(a0, pb[0], o[dt], 0, 0, 0);
            o[dt] = __builtin_amdgcn_mfma_f32_32x32x16_bf16(a1, pb[1], o[dt], 0, 0, 0);
        }

        __syncthreads();
        cur ^= 1;
    }

    // epilogue: write O^T partials [p][d][q] (coalesced over q)
    #pragma unroll
    for (int dt = 0; dt < 8; ++dt) {
        #pragma unroll
        for (int i = 0; i < 16; ++i) {
            const int dg = dt * 32 + (i & 3) + 8 * (i >> 2) + 4 * h;
            outpT[((size_t)p * DD + dg) * NN + q0 + w * 32 + l31] = o[dt][i];
        }
    }
    if (h == 0) {
        statm[(size_t)p * NN + q0 + w * 32 + l31] = mrun;
        statl[(size_t)p * NN + q0 + w * 32 + l31] = lrun;
    }
}

// ---------------- combine O^T partials -> out[q][d] ----------------
// grid: 256 blocks x 256 threads; block = 32-q tile
__global__ __launch_bounds__(256) void combine_kernel(
    const float* __restrict__ outpT, const float* __restrict__ statm,
    const float* __restrict__ statl, float* __restrict__ out)
{
    __shared__ float Wn[NPART][QT];
    __shared__ float Ot[QT][DD + 4];

    const int q0 = blockIdx.x * QT;
    const int tid = threadIdx.x;

    if (tid < QT) {
        const int q = q0 + tid;
        float mv[NPART], lv[NPART];
        float mM = -1e30f;
        #pragma unroll
        for (int p = 0; p < NPART; ++p) {
            mv[p] = statm[(size_t)p * NN + q];
            lv[p] = statl[(size_t)p * NN + q];
            mM = fmaxf(mM, mv[p]);
        }
        float L = 0.f;
        float wg[NPART];
        #pragma unroll
        for (int p = 0; p < NPART; ++p) {
            wg[p] = exp2f(mv[p] - mM);
            L += wg[p] * lv[p];
        }
        const float inv = 1.0f / L;
        #pragma unroll
        for (int p = 0; p < NPART; ++p) Wn[p][tid] = wg[p] * inv;
    }
    __syncthreads();

    {
        const int q = tid & 31;
        const int ds = tid >> 5;
        #pragma unroll 4
        for (int d = ds; d < DD; d += 8) {
            float acc = 0.f;
            #pragma unroll
            for (int p = 0; p < NPART; ++p)
                acc += Wn[p][q] * outpT[((size_t)p * DD + d) * NN + q0 + q];
            Ot[q][d] = acc;
        }
    }
    __syncthreads();

    {
        const int qq = tid >> 3;
        const int c = tid & 7;
        #pragma unroll
        for (int j = 0; j < 8; ++j) {
            const int d = c * 32 + j * 4;
            *reinterpret_cast<f32x4*>(&out[(size_t)(q0 + qq) * DD + d]) =
                *reinterpret_cast<const f32x4*>(&Ot[qq][d]);
        }
    }
}

extern "C" void kernel_launch(void* const* d_in, const int* in_sizes, int n_in,
                              void* d_out, int out_size, void* d_ws, size_t ws_size,
                              hipStream_t stream) {
    const float* xq  = (const float*)d_in[0];
    const float* xkv = (const float*)d_in[1];
    const float* Wq  = (const float*)d_in[2];
    const float* bq  = (const float*)d_in[3];
    const float* Wk  = (const float*)d_in[4];
    const float* bk  = (const float*)d_in[5];
    const float* Wv  = (const float*)d_in[6];
    const float* bv  = (const float*)d_in[7];
    float* out = (float*)d_out;

    char* ws = (char*)d_ws;
    short* qb  = (short*)(ws);                        // 4 MiB bf16 q (pre-scaled)
    short* kb  = (short*)(ws + ((size_t)4 << 20));    // 4 MiB bf16 k
    short* vpb = (short*)(ws + ((size_t)8 << 20));    // 4 MiB bf16 V panels [M/32][256][32]
    float* outpT = (float*)(ws + ((size_t)12 << 20)); // 64 MiB partials [NPART][D][N]
    float* sm = (float*)(ws + ((size_t)12 << 20) + (size_t)NPART * NN * DD * 4);
    float* sl = sm + (size_t)NPART * NN;

    hipFuncSetAttribute(reinterpret_cast<const void*>(attn_kernel),
                        hipFuncAttributeMaxDynamicSharedMemorySize, 65536);

    proj_kernel<<<1536, 256, 0, stream>>>(xq, xkv, Wq, bq, Wk, bk, Wv, bv, qb, kb, vpb);
    attn_kernel<<<512, 256, 65536, stream>>>(qb, kb, vpb, outpT, sm, sl);
    combine_kernel<<<NN / QT, 256, 0, stream>>>(outpT, sm, sl, out);
}

// Round 9
// 140.254 us; speedup vs baseline: 1.1510x; 1.1510x over previous
//
#include <hip/hip_runtime.h>

#define NN 8192
#define MM 8192
#define DD 256
#define NPART 8
#define MPART (MM / NPART)   // 1024
#define BK 64
#define NT (MPART / BK)      // 16
#define QT 32
#define TILE_SH 16384        // shorts per 32KB tile buffer

typedef short bf16x8 __attribute__((ext_vector_type(8)));
typedef short bf16x4 __attribute__((ext_vector_type(4)));
typedef float f32x4 __attribute__((ext_vector_type(4)));
typedef float f32x16 __attribute__((ext_vector_type(16)));
typedef unsigned int u32;
typedef u32 u32x4 __attribute__((ext_vector_type(4)));

#define GLL16(src, dst) __builtin_amdgcn_global_load_lds( \
    (__attribute__((address_space(1))) void*)(src), \
    (__attribute__((address_space(3))) void*)(dst), 16, 0, 0)

static __device__ __forceinline__ short f2bf(float f) {
    unsigned u = __float_as_uint(f);
    u += 0x7fffu + ((u >> 16) & 1u);   // RNE
    return (short)(u >> 16);
}

static __device__ __forceinline__ u32 cvtpk(float lo, float hi) {
    u32 r;
    asm("v_cvt_pk_bf16_f32 %0, %1, %2" : "=v"(r) : "v"(lo), "v"(hi));
    return r;
}

// ---------------- projection: y = x @ W^T + b  -> bf16 ----------------
// grid 1536 = 3 mats x 128 row-tiles x 4 col-tiles; 256 threads
__global__ __launch_bounds__(256, 2) void proj_kernel(
    const float* __restrict__ xq, const float* __restrict__ xkv,
    const float* __restrict__ Wq, const float* __restrict__ bq,
    const float* __restrict__ Wk, const float* __restrict__ bk,
    const float* __restrict__ Wv, const float* __restrict__ bv,
    short* __restrict__ qo, short* __restrict__ ko, short* __restrict__ vp)
{
    __shared__ short Xs[64][264];
    __shared__ short Ws[64][264];

    const int bid = blockIdx.x;
    const int mat = bid >> 9;
    const int t = bid & 511;
    const int rt = t >> 2;
    const int ct = t & 3;
    const float* __restrict__ X = (mat == 0) ? xq : xkv;
    const float* __restrict__ W = (mat == 0) ? Wq : ((mat == 1) ? Wk : Wv);
    const float* __restrict__ bias = (mat == 0) ? bq : ((mat == 1) ? bk : bv);

    const int tid = threadIdx.x;
    const int lane = tid & 63;
    const int wv = tid >> 6;
    const int l15 = lane & 15;
    const int lg = lane >> 4;

    #pragma unroll
    for (int i = 0; i < 16; ++i) {
        int c = i * 256 + tid;
        int row = c >> 6;
        int col4 = (c & 63) << 2;
        f32x4 xv = *reinterpret_cast<const f32x4*>(X + (size_t)(rt * 64 + row) * DD + col4);
        f32x4 wr = *reinterpret_cast<const f32x4*>(W + (size_t)(ct * 64 + row) * DD + col4);
        bf16x4 xb, wb;
        #pragma unroll
        for (int j = 0; j < 4; ++j) { xb[j] = f2bf(xv[j]); wb[j] = f2bf(wr[j]); }
        *reinterpret_cast<bf16x4*>(&Xs[row][col4]) = xb;
        *reinterpret_cast<bf16x4*>(&Ws[row][col4]) = wb;
    }
    __syncthreads();

    f32x4 acc[4];
    #pragma unroll
    for (int f = 0; f < 4; ++f) acc[f] = f32x4{0.f, 0.f, 0.f, 0.f};

    #pragma unroll
    for (int kk = 0; kk < 8; ++kk) {
        bf16x8 a = *reinterpret_cast<const bf16x8*>(&Xs[wv * 16 + l15][kk * 32 + lg * 8]);
        #pragma unroll
        for (int f = 0; f < 4; ++f) {
            bf16x8 b = *reinterpret_cast<const bf16x8*>(&Ws[f * 16 + l15][kk * 32 + lg * 8]);
            acc[f] = __builtin_amdgcn_mfma_f32_16x16x32_bf16(a, b, acc[f], 0, 0, 0);
        }
    }

    #pragma unroll
    for (int f = 0; f < 4; ++f) {
        const int o = ct * 64 + f * 16 + l15;
        const float bsv = bias[o];
        if (mat == 2) {
            // V panels: vp[(m>>6)*16384 + d*64 + (m&63)]
            bf16x4 pk;
            #pragma unroll
            for (int r = 0; r < 4; ++r) pk[r] = f2bf(acc[f][r] + bsv);
            const int mb = rt * 64 + wv * 16 + lg * 4;
            *reinterpret_cast<bf16x4*>(&vp[(size_t)(mb >> 6) * 16384 + o * 64 + (mb & 63)]) = pk;
        } else {
            // q: fold 1/sqrt(D)=1/16 and log2(e) (softmax in exp2 domain)
            const float sc = (mat == 0) ? 0.0625f * 1.44269504089f : 1.0f;
            short* __restrict__ dst = (mat == 0) ? qo : ko;
            #pragma unroll
            for (int r = 0; r < 4; ++r) {
                const int rowg = rt * 64 + wv * 16 + lg * 4 + r;
                dst[(size_t)rowg * DD + o] = f2bf((acc[f][r] + bsv) * sc);
            }
        }
    }
}

// ---------------- flash attention: BK=64, 8 waves, K x3 / V x2 buffers, counted vmcnt ----------------
// grid: 256 = 32 q-tiles(256 q) x 8 parts; 512 threads (8 waves x 32 q/wave)
// LDS: 3*32KB K + 2*32KB V = 160 KB exactly (max workgroup LDS).
__global__ __launch_bounds__(512, 2) void attn_kernel(
    const short* __restrict__ qg, const short* __restrict__ kg,
    const short* __restrict__ vp, float* __restrict__ outpT,
    float* __restrict__ statm, float* __restrict__ statl)
{
    extern __shared__ short lds[];
    short* KsBase = lds;                 // 3 x 16384 shorts: [m 64][512B], phys chunk = log ^ (m&15)
    short* VsBase = lds + 3 * TILE_SH;   // 2 x 16384 shorts: [d 256][128B], phys chunk rotate (d&7)

    const int bid = blockIdx.x;
    const int p = bid & 7;
    const int qt = bid >> 3;
    const int q0 = qt * 256;
    const int tile0 = p * NT;

    const int tid = threadIdx.x;
    const int lane = tid & 63;
    const int w = tid >> 6;
    const int l31 = lane & 31;
    const int h = lane >> 5;

    // Q B-frags: qf[kt] = Q[q0+w*32+l31][kt*16 + h*8 .. +7]
    bf16x8 qf[16];
    {
        const short* qr = qg + (size_t)(q0 + w * 32 + l31) * DD + h * 8;
        #pragma unroll
        for (int kt = 0; kt < 16; ++kt)
            qf[kt] = *reinterpret_cast<const bf16x8*>(qr + kt * 16);
    }

    // staging source offsets (shorts), pre-permuted for swizzled LDS reads
    int koff[4], voff[4], jdst[4];
    #pragma unroll
    for (int i = 0; i < 4; ++i) {
        const int j = w * 4 + i;                  // 0..31
        const int m = 2 * j + h;                  // K row
        koff[i] = m * 256 + ((l31 ^ (m & 15)) << 3);
        const int d = j * 8 + (lane >> 3);        // V row
        const int cl = ((lane & 7) - (d & 7)) & 7;
        voff[i] = d * 64 + (cl << 3);
        jdst[i] = __builtin_amdgcn_readfirstlane(j * 512);
    }

    f32x16 o[8];
    #pragma unroll
    for (int dt = 0; dt < 8; ++dt)
        #pragma unroll
        for (int i = 0; i < 16; ++i) o[dt][i] = 0.f;
    float mrun = -1e30f, lrun = 0.f;

    // prologue: K(0)->Kbuf0, V(0)->Vbuf0, K(1)->Kbuf1 (12 loads);
    // wait K0+V0 (leave K1's 4 in flight); barrier
    #pragma unroll
    for (int i = 0; i < 4; ++i) {
        GLL16(kg + (size_t)tile0 * 16384 + koff[i], KsBase + jdst[i]);
        GLL16(vp + (size_t)tile0 * 16384 + voff[i], VsBase + jdst[i]);
    }
    #pragma unroll
    for (int i = 0; i < 4; ++i)
        GLL16(kg + (size_t)(tile0 + 1) * 16384 + koff[i], KsBase + TILE_SH + jdst[i]);
    asm volatile("s_waitcnt vmcnt(4)\n\ts_barrier" ::: "memory");

    int kR = 0, kN = 1, kW = 2;
    #pragma unroll 1
    for (int t = 0; t < NT; ++t) {
        const char* kb = (const char*)(KsBase + kR * TILE_SH);
        const char* vb = (const char*)(VsBase + (t & 1) * TILE_SH);

        // issue V(t+1) into the V buffer read at t-1 (freed by last barrier)
        if (t + 1 < NT) {
            const size_t tb = (size_t)(tile0 + t + 1) * 16384;
            short* vd = VsBase + ((t + 1) & 1) * TILE_SH;
            #pragma unroll
            for (int i = 0; i < 4; ++i) GLL16(vp + tb + voff[i], vd + jdst[i]);
        }
        // issue K(t+2) into the K buffer read at t-1
        if (t + 2 < NT) {
            const size_t tb = (size_t)(tile0 + t + 2) * 16384;
            short* kd = KsBase + kW * TILE_SH;
            #pragma unroll
            for (int i = 0; i < 4; ++i) GLL16(kg + tb + koff[i], kd + jdst[i]);
        }

        // S^T = K · Q^T : two independent 16-deep chains (m 0..31, m 32..63)
        f32x16 sL, sH;
        #pragma unroll
        for (int i = 0; i < 16; ++i) { sL[i] = 0.f; sH[i] = 0.f; }
        __builtin_amdgcn_s_setprio(1);
        #pragma unroll
        for (int kt = 0; kt < 16; ++kt) {
            const int cb = ((kt * 2 + h) ^ (l31 & 15)) << 4;
            bf16x8 aL = *reinterpret_cast<const bf16x8*>(kb + l31 * 512 + cb);
            bf16x8 aH = *reinterpret_cast<const bf16x8*>(kb + (32 + l31) * 512 + cb);
            sL = __builtin_amdgcn_mfma_f32_32x32x16_bf16(aL, qf[kt], sL, 0, 0, 0);
            sH = __builtin_amdgcn_mfma_f32_32x32x16_bf16(aH, qf[kt], sH, 0, 0, 0);
        }
        __builtin_amdgcn_s_setprio(0);

        // softmax over m (64 per q); q = l31 lane-local
        float mx;
        {
            float a0 = fmaxf(fmaxf(sL[0], sL[1]), fmaxf(sL[2], sL[3]));
            float a1 = fmaxf(fmaxf(sL[4], sL[5]), fmaxf(sL[6], sL[7]));
            float a2 = fmaxf(fmaxf(sL[8], sL[9]), fmaxf(sL[10], sL[11]));
            float a3 = fmaxf(fmaxf(sL[12], sL[13]), fmaxf(sL[14], sL[15]));
            float b0 = fmaxf(fmaxf(sH[0], sH[1]), fmaxf(sH[2], sH[3]));
            float b1 = fmaxf(fmaxf(sH[4], sH[5]), fmaxf(sH[6], sH[7]));
            float b2 = fmaxf(fmaxf(sH[8], sH[9]), fmaxf(sH[10], sH[11]));
            float b3 = fmaxf(fmaxf(sH[12], sH[13]), fmaxf(sH[14], sH[15]));
            mx = fmaxf(fmaxf(fmaxf(a0, a1), fmaxf(a2, a3)),
                       fmaxf(fmaxf(b0, b1), fmaxf(b2, b3)));
            mx = fmaxf(mx, __shfl_xor(mx, 32));
        }
        if (__any(mx > mrun + 11.5f)) {       // defer-max (log2 domain)
            const float mn = fmaxf(mrun, mx);
            const float al = __builtin_amdgcn_exp2f(mrun - mn);
            mrun = mn;
            lrun *= al;
            #pragma unroll
            for (int dt = 0; dt < 8; ++dt)
                #pragma unroll
                for (int i = 0; i < 16; ++i) o[dt][i] *= al;
        }
        #pragma unroll
        for (int i = 0; i < 16; ++i) {
            sL[i] = __builtin_amdgcn_exp2f(sL[i] - mrun);
            sH[i] = __builtin_amdgcn_exp2f(sH[i] - mrun);
        }
        {
            float r0 = ((sL[0] + sL[1]) + (sL[2] + sL[3])) + ((sL[4] + sL[5]) + (sL[6] + sL[7]));
            float r1 = ((sL[8] + sL[9]) + (sL[10] + sL[11])) + ((sL[12] + sL[13]) + (sL[14] + sL[15]));
            float r2 = ((sH[0] + sH[1]) + (sH[2] + sH[3])) + ((sH[4] + sH[5]) + (sH[6] + sH[7]));
            float r3 = ((sH[8] + sH[9]) + (sH[10] + sH[11])) + ((sH[12] + sH[13]) + (sH[14] + sH[15]));
            float rs = (r0 + r1) + (r2 + r3);
            rs += __shfl_xor(rs, 32);
            lrun += rs;
        }

        // P -> 4 B-frags (m 0..15, 16..31, 32..47, 48..63)
        bf16x8 pb[4];
        #pragma unroll
        for (int half = 0; half < 2; ++half) {
            const f32x16& sv = half ? sH : sL;
            #pragma unroll
            for (int g = 0; g < 2; ++g) {
                u32 pa = cvtpk(sv[g * 8 + 0], sv[g * 8 + 1]);
                u32 pbq = cvtpk(sv[g * 8 + 2], sv[g * 8 + 3]);
                u32 pc = cvtpk(sv[g * 8 + 4], sv[g * 8 + 5]);
                u32 pd = cvtpk(sv[g * 8 + 6], sv[g * 8 + 7]);
                const u32 xa = (u32)__shfl_xor((int)pa, 32);
                const u32 xb = (u32)__shfl_xor((int)pbq, 32);
                const u32 xc = (u32)__shfl_xor((int)pc, 32);
                const u32 xd = (u32)__shfl_xor((int)pd, 32);
                u32x4 bb;
                bb[0] = h ? xc : pa;
                bb[1] = h ? xd : pbq;
                bb[2] = h ? pc : xa;
                bb[3] = h ? pd : xb;
                pb[half * 2 + g] = __builtin_bit_cast(bf16x8, bb);
            }
        }

        // O^T[d 256][q 32] += V^T · P (8 independent 4-chains)
        __builtin_amdgcn_s_setprio(1);
        #pragma unroll
        for (int dt = 0; dt < 8; ++dt) {
            const int d = dt * 32 + l31;
            const char* rbase = vb + d * 128;
            const int rot = d & 7;
            bf16x8 a0 = *reinterpret_cast<const bf16x8*>(rbase + (((0 + h + rot) & 7) << 4));
            bf16x8 a1 = *reinterpret_cast<const bf16x8*>(rbase + (((2 + h + rot) & 7) << 4));
            bf16x8 a2 = *reinterpret_cast<const bf16x8*>(rbase + (((4 + h + rot) & 7) << 4));
            bf16x8 a3 = *reinterpret_cast<const bf16x8*>(rbase + (((6 + h + rot) & 7) << 4));
            o[dt] = __builtin_amdgcn_mfma_f32_32x32x16_bf16(a0, pb[0], o[dt], 0, 0, 0);
            o[dt] = __builtin_amdgcn_mfma_f32_32x32x16_bf16(a1, pb[1], o[dt], 0, 0, 0);
            o[dt] = __builtin_amdgcn_mfma_f32_32x32x16_bf16(a2, pb[2], o[dt], 0, 0, 0);
            o[dt] = __builtin_amdgcn_mfma_f32_32x32x16_bf16(a3, pb[3], o[dt], 0, 0, 0);
        }
        __builtin_amdgcn_s_setprio(0);

        // counted wait: K(t+1)+V(t+1) (oldest 8) done; K(t+2)'s 4 stay in flight
        if (t + 2 < NT) {
            asm volatile("s_waitcnt vmcnt(4)\n\ts_barrier" ::: "memory");
        } else if (t + 1 < NT) {
            asm volatile("s_waitcnt vmcnt(0)\n\ts_barrier" ::: "memory");
        }
        const int tmp = kR; kR = kN; kN = kW; kW = tmp;
    }

    // epilogue: write O^T partials [p][d][q] (coalesced over q)
    #pragma unroll
    for (int dt = 0; dt < 8; ++dt) {
        #pragma unroll
        for (int i = 0; i < 16; ++i) {
            const int dg = dt * 32 + (i & 3) + 8 * (i >> 2) + 4 * h;
            outpT[((size_t)p * DD + dg) * NN + q0 + w * 32 + l31] = o[dt][i];
        }
    }
    if (h == 0) {
        statm[(size_t)p * NN + q0 + w * 32 + l31] = mrun;
        statl[(size_t)p * NN + q0 + w * 32 + l31] = lrun;
    }
}

// ---------------- combine O^T partials -> out[q][d] ----------------
// grid: 256 blocks x 256 threads; block = 32-q tile
__global__ __launch_bounds__(256) void combine_kernel(
    const float* __restrict__ outpT, const float* __restrict__ statm,
    const float* __restrict__ statl, float* __restrict__ out)
{
    __shared__ float Wn[NPART][QT];
    __shared__ float Ot[QT][DD + 4];

    const int q0 = blockIdx.x * QT;
    const int tid = threadIdx.x;

    if (tid < QT) {
        const int q = q0 + tid;
        float mv[NPART], lv[NPART];
        float mM = -1e30f;
        #pragma unroll
        for (int p = 0; p < NPART; ++p) {
            mv[p] = statm[(size_t)p * NN + q];
            lv[p] = statl[(size_t)p * NN + q];
            mM = fmaxf(mM, mv[p]);
        }
        float L = 0.f;
        float wg[NPART];
        #pragma unroll
        for (int p = 0; p < NPART; ++p) {
            wg[p] = exp2f(mv[p] - mM);
            L += wg[p] * lv[p];
        }
        const float inv = 1.0f / L;
        #pragma unroll
        for (int p = 0; p < NPART; ++p) Wn[p][tid] = wg[p] * inv;
    }
    __syncthreads();

    {
        const int q = tid & 31;
        const int ds = tid >> 5;
        #pragma unroll 4
        for (int d = ds; d < DD; d += 8) {
            float acc = 0.f;
            #pragma unroll
            for (int p = 0; p < NPART; ++p)
                acc += Wn[p][q] * outpT[((size_t)p * DD + d) * NN + q0 + q];
            Ot[q][d] = acc;
        }
    }
    __syncthreads();

    {
        const int qq = tid >> 3;
        const int c = tid & 7;
        #pragma unroll
        for (int j = 0; j < 8; ++j) {
            const int d = c * 32 + j * 4;
            *reinterpret_cast<f32x4*>(&out[(size_t)(q0 + qq) * DD + d]) =
                *reinterpret_cast<const f32x4*>(&Ot[qq][d]);
        }
    }
}

extern "C" void kernel_launch(void* const* d_in, const int* in_sizes, int n_in,
                              void* d_out, int out_size, void* d_ws, size_t ws_size,
                              hipStream_t stream) {
    const float* xq  = (const float*)d_in[0];
    const float* xkv = (const float*)d_in[1];
    const float* Wq  = (const float*)d_in[2];
    const float* bq  = (const float*)d_in[3];
    const float* Wk  = (const float*)d_in[4];
    const float* bk  = (const float*)d_in[5];
    const float* Wv  = (const float*)d_in[6];
    const float* bv  = (const float*)d_in[7];
    float* out = (float*)d_out;

    char* ws = (char*)d_ws;
    short* qb  = (short*)(ws);                        // 4 MiB bf16 q (pre-scaled)
    short* kb  = (short*)(ws + ((size_t)4 << 20));    // 4 MiB bf16 k
    short* vpb = (short*)(ws + ((size_t)8 << 20));    // 4 MiB bf16 V panels [M/64][256][64]
    float* outpT = (float*)(ws + ((size_t)12 << 20)); // 64 MiB partials [NPART][D][N]
    float* sm = (float*)(ws + ((size_t)12 << 20) + (size_t)NPART * NN * DD * 4);
    float* sl = sm + (size_t)NPART * NN;

    hipFuncSetAttribute(reinterpret_cast<const void*>(attn_kernel),
                        hipFuncAttributeMaxDynamicSharedMemorySize, 163840);

    proj_kernel<<<1536, 256, 0, stream>>>(xq, xkv, Wq, bq, Wk, bk, Wv, bv, qb, kb, vpb);
    attn_kernel<<<256, 512, 163840, stream>>>(qb, kb, vpb, outpT, sm, sl);
    combine_kernel<<<NN / QT, 256, 0, stream>>>(outpT, sm, sl, out);
}